// Round 9
// baseline (497.227 us; speedup 1.0000x reference)
//
#include <hip/hip_runtime.h>
#include <hip/hip_bf16.h>
#include <math.h>

// Problem sizes (fixed by the reference)
constexpr int Bn  = 32;
constexpr int LK  = 2048;
constexpr int Dn  = 32;
constexpr int LQ  = 128;
constexpr int ET  = 128;
constexpr int Hn  = 8;
constexpr int ETK = 16;
constexpr int NH  = 128;

typedef __attribute__((ext_vector_type(8)))  short bf16x8;
typedef __attribute__((ext_vector_type(16))) float f32x16;

__device__ __forceinline__ float hsum4(float4 v){ return (v.x+v.y)+(v.z+v.w); }
__device__ __forceinline__ void fma4(float4& s, const float4 a, const float4 b){
  s.x = fmaf(a.x,b.x,s.x); s.y = fmaf(a.y,b.y,s.y);
  s.z = fmaf(a.z,b.z,s.z); s.w = fmaf(a.w,b.w,s.w);
}
__device__ __forceinline__ unsigned short bfu(float a){
  __hip_bfloat16 h = __float2bfloat16(a);
  unsigned short u; __builtin_memcpy(&u, &h, 2); return u;
}
__device__ __forceinline__ unsigned pkbf(float a, float b){
  return (unsigned)bfu(a) | ((unsigned)bfu(b) << 16);
}

// ---------------------------------------------------------------------------
// Kernel 0: x (B,LK,32) f32  ->  xT (B,32,LK) bf16.  grid = B*32 (64-key tiles)
// ---------------------------------------------------------------------------
__global__ __launch_bounds__(256) void xt_kernel(
    const float* __restrict__ x, __hip_bfloat16* __restrict__ xT)
{
  __shared__ float tile[32][65];
  const int wg = blockIdx.x;
  const int b = wg >> 5, kt = wg & 31;
  const int k0 = kt*64;
  const int t = threadIdx.x;
  const float4* src = (const float4*)(x + ((size_t)b*LK + k0)*Dn);
  const float4 v0 = src[t*2], v1 = src[t*2+1];
  const int r = t>>2, c0 = (t&3)*8;
  tile[c0+0][r]=v0.x; tile[c0+1][r]=v0.y; tile[c0+2][r]=v0.z; tile[c0+3][r]=v0.w;
  tile[c0+4][r]=v1.x; tile[c0+5][r]=v1.y; tile[c0+6][r]=v1.z; tile[c0+7][r]=v1.w;
  __syncthreads();
  const int d = t>>3, o = (t&7)*8;
  uint4 w;
  w.x = pkbf(tile[d][o+0], tile[d][o+1]);
  w.y = pkbf(tile[d][o+2], tile[d][o+3]);
  w.z = pkbf(tile[d][o+4], tile[d][o+5]);
  w.w = pkbf(tile[d][o+6], tile[d][o+7]);
  *(uint4*)(xT + ((size_t)(b*Dn + d))*LK + k0 + o) = w;
}

// ---------------------------------------------------------------------------
// Kernel 1: time embedding + Q/K projection -> bf16.  (0.25 folded into Q)
// grid = 512 K-blocks (128 rows each) + 1 Q-block (128 rows); block = 128.
// W staged ONCE in 64 KB LDS (no VGPR-demotion risk); thread (r,half) holds
// emb half-rows for rows r and r+64 in registers; weight reads are 2-address
// broadcasts (2-way bank alias = free). Halves merged via shfl_xor(1).
// ---------------------------------------------------------------------------
__global__ __launch_bounds__(128, 2) void proj_kernel(
    const float* __restrict__ ts, const float* __restrict__ qt,
    const float* __restrict__ Wlin, const float* __restrict__ blin,
    const float* __restrict__ Wper, const float* __restrict__ bper,
    const float* __restrict__ Wq, const float* __restrict__ bq,
    const float* __restrict__ Wk, const float* __restrict__ bk,
    __hip_bfloat16* __restrict__ Kbuf, __hip_bfloat16* __restrict__ Qbuf)
{
  __shared__ __align__(16) float Wl[ET*ET];   // 64 KB
  const int wg  = blockIdx.x;                 // 0..511 K, 512 = Q
  const int tid = threadIdx.x;
  const bool isq = (wg == 512);
  const int row0 = isq ? 0 : wg*128;
  const float* W    = isq ? Wq : Wk;
  const float* bias = isq ? bq : bk;
  const int r = tid >> 1, half = tid & 1;

  { // stage W coalesced
    const float4* Wg4 = (const float4*)W;
    float4* Wl4 = (float4*)Wl;
    #pragma unroll
    for (int i=0;i<32;i++) Wl4[tid + i*128] = Wg4[tid + i*128];
  }

  // emb half-rows (cols half*64..+63) for rows r and r+64, in registers
  const float t0 = isq ? qt[row0+r]      : ts[row0+r];
  const float t1 = isq ? qt[row0+r+64]   : ts[row0+r+64];
  float4 e0[16], e1[16];
  {
    const float wl0 = Wlin[0], bl0 = blin[0];
    #pragma unroll
    for (int i=0;i<16;i++){
      float a[4], c4[4];
      #pragma unroll
      for (int k2=0;k2<4;k2++){
        const int c = half*64 + i*4 + k2;
        if (c == 0){ a[k2] = fmaf(t0, wl0, bl0); c4[k2] = fmaf(t1, wl0, bl0); }
        else {
          const float wp = Wper[c-1], bp = bper[c-1];
          a[k2]  = __sinf(fmaf(t0, wp, bp));
          c4[k2] = __sinf(fmaf(t1, wp, bp));
        }
      }
      e0[i] = make_float4(a[0],a[1],a[2],a[3]);
      e1[i] = make_float4(c4[0],c4[1],c4[2],c4[3]);
    }
  }
  __syncthreads();

  for (int o=0;o<128;o++){
    const float4* wr = (const float4*)(Wl + o*ET + half*64);  // broadcast (2 addrs)
    float4 a0={0,0,0,0}, a1={0,0,0,0}, b0={0,0,0,0}, b1={0,0,0,0};
    #pragma unroll
    for (int i=0;i<8;i++){
      const float4 w0 = wr[2*i], w1 = wr[2*i+1];
      fma4(a0, w0, e0[2*i]); fma4(a1, w1, e0[2*i+1]);
      fma4(b0, w0, e1[2*i]); fma4(b1, w1, e1[2*i+1]);
    }
    float s0 = hsum4(a0) + hsum4(a1);
    float s1 = hsum4(b0) + hsum4(b1);
    s0 += __shfl_xor(s0, 1);
    s1 += __shfl_xor(s1, 1);
    if (half == 0){
      const float bb = bias[o];
      if (isq){
        Qbuf[((o>>4)*LQ + r     )*ETK + (o&15)] = __float2bfloat16((s0+bb)*0.25f);
        Qbuf[((o>>4)*LQ + r + 64)*ETK + (o&15)] = __float2bfloat16((s1+bb)*0.25f);
      } else {
        const int row_a = row0 + r, row_b = row0 + r + 64;
        const int ba = row_a >> 11, la = row_a & (LK-1);
        const int bb2 = row_b >> 11, lb = row_b & (LK-1);
        Kbuf[(((ba <<3)+(o>>4))*LK + la)*ETK + (o&15)] = __float2bfloat16(s0+bb);
        Kbuf[(((bb2<<3)+(o>>4))*LK + lb)*ETK + (o&15)] = __float2bfloat16(s1+bb);
      }
    }
  }
}

// ---------------------------------------------------------------------------
// Kernel 2: MFMA flash attention.  grid = B*H = 256 WGs, 256 thr = 4 waves.
// (unchanged — verified this round: absmax 2.4e-4)
// ---------------------------------------------------------------------------
__global__ __launch_bounds__(256, 2) void attn_mfma_kernel(
    const __hip_bfloat16* __restrict__ Kb, const __hip_bfloat16* __restrict__ Qb,
    const __hip_bfloat16* __restrict__ xT, float* __restrict__ attb)
{
  __shared__ uint4 Ks[2][512];    // 256 keys x 16 bf16 (2 units/row)
  __shared__ uint4 Xs[2][1024];   // 32 d x 256 keys (32 units/row)
  const int wgid = blockIdx.x;
  const int b = wgid >> 3, h = wgid & 7;
  const int tid = threadIdx.x;
  const int lane = tid & 63;
  const int ln = lane & 31, hi = lane >> 5;
  const int q0 = (tid >> 6) * 32;

  bf16x8 qf;
  {
    const uint4 u = *(const uint4*)(Qb + ((h*LQ + q0 + ln)*ETK + 8*hi));
    qf = *(const bf16x8*)&u;
  }

  const f32x16 zf = {0.f,0.f,0.f,0.f,0.f,0.f,0.f,0.f,0.f,0.f,0.f,0.f,0.f,0.f,0.f,0.f};
  f32x16 acc = zf;
  float m = -INFINITY, lsum = 0.f;

  const int sd = tid>>3, skb = (tid&7)*4, sdx = sd&7, ksw = (tid>>2)&7;
  const uint4* Kg = (const uint4*)(Kb + ((size_t)(b*Hn + h)*LK)*ETK);
  const uint4* Xg = (const uint4*)(xT + ((size_t)(b*Dn + sd))*LK + (tid&7)*32);

  uint4 kr0, kr1, xr0, xr1, xr2, xr3;
  {
    const uint4* kp = Kg + tid*2;
    kr0 = kp[0]; kr1 = kp[1];
    xr0 = Xg[0]; xr1 = Xg[1]; xr2 = Xg[2]; xr3 = Xg[3];
    Ks[0][(2*tid  ) ^ ksw] = kr0;
    Ks[0][(2*tid+1) ^ ksw] = kr1;
    Xs[0][sd*32 + ((skb+0)^sdx)] = xr0;
    Xs[0][sd*32 + ((skb+1)^sdx)] = xr1;
    Xs[0][sd*32 + ((skb+2)^sdx)] = xr2;
    Xs[0][sd*32 + ((skb+3)^sdx)] = xr3;
  }
  __syncthreads();

  for (int ck = 0; ck < 8; ck++){
    const int cur = ck & 1, nxt = cur ^ 1;
    if (ck < 7){
      const uint4* kp = Kg + ((ck+1)*256 + tid)*2;
      kr0 = kp[0]; kr1 = kp[1];
      const uint4* xp = Xg + (ck+1)*32;   // 256 keys = 512 B = 32 uint4 along row
      xr0 = xp[0]; xr1 = xp[1]; xr2 = xp[2]; xr3 = xp[3];
    }

    for (int kt = 0; kt < 8; kt++){
      const int r = kt*32 + ln;
      const uint4 ku = Ks[cur][(2*r + hi) ^ ((r>>2)&7)];
      const bf16x8 kf = *(const bf16x8*)&ku;
      f32x16 s = __builtin_amdgcn_mfma_f32_32x32x16_bf16(kf, qf, zf, 0, 0, 0);

      float tmax = s[0];
      #pragma unroll
      for (int i=1;i<16;i++) tmax = fmaxf(tmax, s[i]);
      tmax = fmaxf(tmax, __shfl_xor(tmax, 32));
      if (__any(tmax > m)){
        const float mn = fmaxf(m, tmax);
        const float al = __expf(m - mn);
        lsum *= al;
        acc *= al;
        m = mn;
      }
      float p[16]; float tsum = 0.f;
      #pragma unroll
      for (int i=0;i<16;i++){ p[i] = __expf(s[i] - m); tsum += p[i]; }
      tsum += __shfl_xor(tsum, 32);
      lsum += tsum;

      unsigned w0=pkbf(p[0],p[1]),  w1=pkbf(p[2],p[3]),  w2=pkbf(p[4],p[5]),  w3=pkbf(p[6],p[7]);
      unsigned w4=pkbf(p[8],p[9]),  w5=pkbf(p[10],p[11]),w6=pkbf(p[12],p[13]),w7=pkbf(p[14],p[15]);
      unsigned pw0=__shfl_xor(w0,32), pw1=__shfl_xor(w1,32), pw2=__shfl_xor(w2,32), pw3=__shfl_xor(w3,32);
      unsigned pw4=__shfl_xor(w4,32), pw5=__shfl_xor(w5,32), pw6=__shfl_xor(w6,32), pw7=__shfl_xor(w7,32);
      uint4 fa, fb;
      fa.x = hi ? pw2 : w0;  fa.y = hi ? pw3 : w1;
      fa.z = hi ? w2  : pw0; fa.w = hi ? w3  : pw1;
      fb.x = hi ? pw6 : w4;  fb.y = hi ? pw7 : w5;
      fb.z = hi ? w6  : pw4; fb.w = hi ? w7  : pw5;

      const int du = ln*32, dx = ln&7;
      const uint4 xa = Xs[cur][du + ((kt*4 + hi    )^dx)];
      const uint4 xb = Xs[cur][du + ((kt*4 + 2 + hi)^dx)];
      acc = __builtin_amdgcn_mfma_f32_32x32x16_bf16(*(const bf16x8*)&xa, *(const bf16x8*)&fa, acc, 0, 0, 0);
      acc = __builtin_amdgcn_mfma_f32_32x32x16_bf16(*(const bf16x8*)&xb, *(const bf16x8*)&fb, acc, 0, 0, 0);
    }

    if (ck < 7){
      Ks[nxt][(2*tid  ) ^ ksw] = kr0;
      Ks[nxt][(2*tid+1) ^ ksw] = kr1;
      Xs[nxt][sd*32 + ((skb+0)^sdx)] = xr0;
      Xs[nxt][sd*32 + ((skb+1)^sdx)] = xr1;
      Xs[nxt][sd*32 + ((skb+2)^sdx)] = xr2;
      Xs[nxt][sd*32 + ((skb+3)^sdx)] = xr3;
    }
    __syncthreads();
  }

  const float inv = 1.f / lsum;
  float* dst = attb + ((size_t)(b*LQ + q0 + ln)*(Hn*Dn) + h*Dn + 4*hi);
  #pragma unroll
  for (int g=0; g<4; g++){
    float4 v;
    v.x = acc[4*g+0]*inv; v.y = acc[4*g+1]*inv;
    v.z = acc[4*g+2]*inv; v.w = acc[4*g+3]*inv;
    *(float4*)(dst + g*8) = v;
  }
}

// ---------------------------------------------------------------------------
// Kernel 4: out = att @ Wo^T + bo. 16 rows/WG, weight half-rows in VGPRs.
// (min-waves=1 so the 128-VGPR weight array stays register-resident)
// ---------------------------------------------------------------------------
__global__ __launch_bounds__(256, 1) void outproj_kernel(
    const float* __restrict__ att, const float* __restrict__ Wo, const float* __restrict__ bo,
    float* __restrict__ outb)
{
  __shared__ __align__(16) float a[16*256];   // 16 KB
  const int tid = threadIdx.x;
  const int o = tid>>1, half = tid&1;
  float4 w[32];
  {
    const float4* Wr = (const float4*)(Wo + o*256 + half*128);
    #pragma unroll
    for (int i=0;i<32;i++) w[i]=Wr[i];
  }
  const int row0 = blockIdx.x*16;
  {
    const float4* src = (const float4*)(att + (size_t)row0*256);
    float4* a4 = (float4*)a;
    #pragma unroll
    for (int i=0;i<4;i++) a4[tid + i*256] = src[tid + i*256];
  }
  __syncthreads();
  for (int r=0;r<16;r++){
    const float4* ar = (const float4*)(a + r*256 + half*128);
    float4 s4 = {0,0,0,0};
    #pragma unroll
    for (int i=0;i<32;i++) fma4(s4, w[i], ar[i]);
    float s = hsum4(s4);
    s += __shfl_xor(s, 1);
    if (half==0) outb[(size_t)(row0+r)*NH + o] = s + bo[o];
  }
}

// ---------------------------------------------------------------------------
// Kernel 5: x_gates = out @ W_ih^T + b_ih. 384 threads, full rows in VGPRs.
// ---------------------------------------------------------------------------
__global__ __launch_bounds__(384, 1) void gates_kernel(
    const float* __restrict__ outb, const float* __restrict__ W_ih, const float* __restrict__ b_ih,
    float* __restrict__ gates)
{
  __shared__ __align__(16) float a[16*128];   // 8 KB
  const int tid = threadIdx.x;
  float4 w[32];
  {
    const float4* Wr = (const float4*)(W_ih + (size_t)tid*NH);
    #pragma unroll
    for (int i=0;i<32;i++) w[i]=Wr[i];
  }
  const float bi = b_ih[tid];
  const int row0 = blockIdx.x*16;
  {
    const float4* src = (const float4*)(outb + (size_t)row0*NH);
    float4* a4 = (float4*)a;
    for (int i=tid; i<512; i+=384) a4[i] = src[i];
  }
  __syncthreads();
  for (int r=0;r<16;r++){
    const float4* ar = (const float4*)(a + r*NH);
    float4 s0={0,0,0,0}, s1={0,0,0,0};
    #pragma unroll
    for (int i=0;i<16;i++){ fma4(s0, w[2*i], ar[2*i]); fma4(s1, w[2*i+1], ar[2*i+1]); }
    gates[(size_t)(row0+r)*384 + tid] = hsum4(s0) + hsum4(s1) + bi;
  }
}

// ---------------------------------------------------------------------------
// Kernel 6: GRU scan (128 steps) + classifier MLP, one WG per batch element.
// 384 threads, one output/thread, full W_hh row (32 float4) in VGPRs
// (launch_bounds(384,1) -> cap 512, no demotion). h read via pure
// same-address broadcasts -> zero bank conflicts (round-8 counter: 3.1M).
// ---------------------------------------------------------------------------
__global__ __launch_bounds__(384, 1) void gru_cls_kernel(
    const float* __restrict__ gates, const float* __restrict__ W_hh, const float* __restrict__ b_hh,
    const float* __restrict__ W1, const float* __restrict__ b1,
    const float* __restrict__ W2, const float* __restrict__ b2,
    const float* __restrict__ W3, const float* __restrict__ b3,
    float* __restrict__ out)
{
  __shared__ __align__(16) float h[128];
  __shared__ __align__(16) float hg[384];
  __shared__ __align__(16) float c1[304];
  __shared__ __align__(16) float c2[304];
  const int b = blockIdx.x, j = threadIdx.x;

  float4 w[32];
  {
    const float4* Wr = (const float4*)(W_hh + (size_t)j*NH);
    #pragma unroll
    for (int i=0;i<32;i++) w[i]=Wr[i];
  }
  const float bh = b_hh[j];

  float gxr=0.f, gxz=0.f, gxn=0.f;
  if (j < 128){
    const size_t gb = (size_t)b*LQ*384 + j;
    gxr = gates[gb]; gxz = gates[gb+128]; gxn = gates[gb+256];
    h[j] = 0.f;
  }
  __syncthreads();

  for (int tt=0; tt<LQ; tt++){
    float nxr=0.f, nxz=0.f, nxn=0.f;
    if (j < 128 && tt+1 < LQ){
      const size_t nb = ((size_t)b*LQ + tt + 1)*384 + j;
      nxr = gates[nb]; nxz = gates[nb+128]; nxn = gates[nb+256];
    }
    const float4* h4 = (const float4*)h;     // broadcast reads, no conflicts
    float4 s0={0,0,0,0}, s1={0,0,0,0}, s2={0,0,0,0}, s3={0,0,0,0};
    #pragma unroll
    for (int i=0;i<8;i++){
      fma4(s0, w[4*i  ], h4[4*i  ]);
      fma4(s1, w[4*i+1], h4[4*i+1]);
      fma4(s2, w[4*i+2], h4[4*i+2]);
      fma4(s3, w[4*i+3], h4[4*i+3]);
    }
    hg[j] = (hsum4(s0)+hsum4(s1)) + (hsum4(s2)+hsum4(s3)) + bh;
    __syncthreads();
    if (j < 128){
      const float r = 1.f/(1.f + __expf(-(gxr + hg[j])));
      const float z = 1.f/(1.f + __expf(-(gxz + hg[j+128])));
      const float n = 1.f - 2.f/(1.f + __expf(2.f*fmaf(r, hg[j+256], gxn)));
      h[j] = (1.f - z)*n + z*h[j];
      gxr = nxr; gxz = nxz; gxn = nxn;
    }
    __syncthreads();
  }

  if (j < 300){
    const float4* Wr1 = (const float4*)(W1 + (size_t)j*128);
    const float4* h4 = (const float4*)h;
    float4 s={0,0,0,0};
    #pragma unroll
    for (int i=0;i<32;i++) fma4(s, Wr1[i], h4[i]);
    c1[j] = fmaxf(hsum4(s) + b1[j], 0.f);
  }
  __syncthreads();
  if (j < 300){
    const float4* Wr2 = (const float4*)(W2 + (size_t)j*300);
    const float4* c14 = (const float4*)c1;
    float4 s={0,0,0,0};
    #pragma unroll
    for (int i=0;i<75;i++) fma4(s, Wr2[i], c14[i]);
    c2[j] = fmaxf(hsum4(s) + b2[j], 0.f);
  }
  __syncthreads();
  if (j < 2){
    const float4* Wr3 = (const float4*)(W3 + (size_t)j*300);
    const float4* c24 = (const float4*)c2;
    float4 s={0,0,0,0};
    #pragma unroll
    for (int i=0;i<75;i++) fma4(s, Wr3[i], c24[i]);
    out[b*2 + j] = hsum4(s) + b3[j];
  }
}

// ---------------------------------------------------------------------------
extern "C" void kernel_launch(void* const* d_in, const int* in_sizes, int n_in,
                              void* d_out, int out_size, void* d_ws, size_t ws_size,
                              hipStream_t stream)
{
  const float* x    = (const float*)d_in[0];
  const float* ts   = (const float*)d_in[1];
  const float* qt   = (const float*)d_in[2];
  const float* Wlin = (const float*)d_in[3];
  const float* blin = (const float*)d_in[4];
  const float* Wper = (const float*)d_in[5];
  const float* bper = (const float*)d_in[6];
  const float* Wq   = (const float*)d_in[7];
  const float* bq   = (const float*)d_in[8];
  const float* Wk   = (const float*)d_in[9];
  const float* bk   = (const float*)d_in[10];
  const float* Wo   = (const float*)d_in[11];
  const float* bo   = (const float*)d_in[12];
  const float* W_ih = (const float*)d_in[13];
  const float* b_ih = (const float*)d_in[14];
  const float* W_hh = (const float*)d_in[15];
  const float* b_hh = (const float*)d_in[16];
  const float* W1   = (const float*)d_in[17];
  const float* b1   = (const float*)d_in[18];
  const float* W2   = (const float*)d_in[19];
  const float* b2   = (const float*)d_in[20];
  const float* W3   = (const float*)d_in[21];
  const float* b3   = (const float*)d_in[22];
  float* out = (float*)d_out;

  // workspace layout
  __hip_bfloat16* Kbb = (__hip_bfloat16*)d_ws;            // B*H*LK*16 = 8,388,608 bf16
  __hip_bfloat16* Qbb = Kbb + 8388608;                    // H*LQ*16   = 16,384 bf16
  __hip_bfloat16* xTb = Qbb + 16384;                      // B*32*LK   = 2,097,152 bf16
  float* attb = (float*)(xTb + 2097152);                  // B*LQ*256  = 1,048,576 f32
  float* outb = attb + 1048576;                           // B*LQ*128  = 524,288 f32
  float* gts  = outb + 524288;                            // B*LQ*384  = 1,572,864 f32
  (void)ws_size; (void)in_sizes; (void)n_in; (void)out_size;

  xt_kernel      <<<dim3(1024), dim3(256), 0, stream>>>(x, xTb);
  proj_kernel    <<<dim3(513),  dim3(128), 0, stream>>>(ts, qt, Wlin, blin, Wper, bper, Wq, bq, Wk, bk, Kbb, Qbb);
  attn_mfma_kernel<<<dim3(256), dim3(256), 0, stream>>>(Kbb, Qbb, xTb, attb);
  outproj_kernel <<<dim3(256),  dim3(256), 0, stream>>>(attb, Wo, bo, outb);
  gates_kernel   <<<dim3(256),  dim3(384), 0, stream>>>(outb, W_ih, b_ih, gts);
  gru_cls_kernel <<<dim3(32),   dim3(384), 0, stream>>>(gts, W_hh, b_hh, W1, b1, W2, b2, W3, b3, out);
}

// Round 10
// 495.432 us; speedup vs baseline: 1.0036x; 1.0036x over previous
//
#include <hip/hip_runtime.h>
#include <hip/hip_bf16.h>
#include <math.h>

// Problem sizes (fixed by the reference)
constexpr int Bn  = 32;
constexpr int LK  = 2048;
constexpr int Dn  = 32;
constexpr int LQ  = 128;
constexpr int ET  = 128;
constexpr int Hn  = 8;
constexpr int ETK = 16;
constexpr int NH  = 128;

typedef __attribute__((ext_vector_type(8)))  short bf16x8;
typedef __attribute__((ext_vector_type(16))) float f32x16;

__device__ __forceinline__ float hsum4(float4 v){ return (v.x+v.y)+(v.z+v.w); }
__device__ __forceinline__ void fma4(float4& s, const float4 a, const float4 b){
  s.x = fmaf(a.x,b.x,s.x); s.y = fmaf(a.y,b.y,s.y);
  s.z = fmaf(a.z,b.z,s.z); s.w = fmaf(a.w,b.w,s.w);
}
__device__ __forceinline__ unsigned short bfu(float a){
  __hip_bfloat16 h = __float2bfloat16(a);
  unsigned short u; __builtin_memcpy(&u, &h, 2); return u;
}
__device__ __forceinline__ unsigned pkbf(float a, float b){
  return (unsigned)bfu(a) | ((unsigned)bfu(b) << 16);
}
__device__ __forceinline__ float rdlane(float v, int l){
  return __uint_as_float(__builtin_amdgcn_readlane(__float_as_uint(v), l));
}

// ---------------------------------------------------------------------------
// Kernel 0: x (B,LK,32) f32  ->  xT (B,32,LK) bf16.  grid = B*32 (64-key tiles)
// ---------------------------------------------------------------------------
__global__ __launch_bounds__(256) void xt_kernel(
    const float* __restrict__ x, __hip_bfloat16* __restrict__ xT)
{
  __shared__ float tile[32][65];
  const int wg = blockIdx.x;
  const int b = wg >> 5, kt = wg & 31;
  const int k0 = kt*64;
  const int t = threadIdx.x;
  const float4* src = (const float4*)(x + ((size_t)b*LK + k0)*Dn);
  const float4 v0 = src[t*2], v1 = src[t*2+1];
  const int r = t>>2, c0 = (t&3)*8;
  tile[c0+0][r]=v0.x; tile[c0+1][r]=v0.y; tile[c0+2][r]=v0.z; tile[c0+3][r]=v0.w;
  tile[c0+4][r]=v1.x; tile[c0+5][r]=v1.y; tile[c0+6][r]=v1.z; tile[c0+7][r]=v1.w;
  __syncthreads();
  const int d = t>>3, o = (t&7)*8;
  uint4 w;
  w.x = pkbf(tile[d][o+0], tile[d][o+1]);
  w.y = pkbf(tile[d][o+2], tile[d][o+3]);
  w.z = pkbf(tile[d][o+4], tile[d][o+5]);
  w.w = pkbf(tile[d][o+6], tile[d][o+7]);
  *(uint4*)(xT + ((size_t)(b*Dn + d))*LK + k0 + o) = w;
}

// ---------------------------------------------------------------------------
// Kernel 1: time embedding + Q/K projection -> bf16.  (0.25 folded into Q)
// grid = 512 K-blocks (128 rows each) + 1 Q-block (128 rows); block = 128.
// (unchanged from round 9 — next profile will rank it)
// ---------------------------------------------------------------------------
__global__ __launch_bounds__(128, 2) void proj_kernel(
    const float* __restrict__ ts, const float* __restrict__ qt,
    const float* __restrict__ Wlin, const float* __restrict__ blin,
    const float* __restrict__ Wper, const float* __restrict__ bper,
    const float* __restrict__ Wq, const float* __restrict__ bq,
    const float* __restrict__ Wk, const float* __restrict__ bk,
    __hip_bfloat16* __restrict__ Kbuf, __hip_bfloat16* __restrict__ Qbuf)
{
  __shared__ __align__(16) float Wl[ET*ET];   // 64 KB
  const int wg  = blockIdx.x;                 // 0..511 K, 512 = Q
  const int tid = threadIdx.x;
  const bool isq = (wg == 512);
  const int row0 = isq ? 0 : wg*128;
  const float* W    = isq ? Wq : Wk;
  const float* bias = isq ? bq : bk;
  const int r = tid >> 1, half = tid & 1;

  { // stage W coalesced
    const float4* Wg4 = (const float4*)W;
    float4* Wl4 = (float4*)Wl;
    #pragma unroll
    for (int i=0;i<32;i++) Wl4[tid + i*128] = Wg4[tid + i*128];
  }

  const float t0 = isq ? qt[row0+r]      : ts[row0+r];
  const float t1 = isq ? qt[row0+r+64]   : ts[row0+r+64];
  float4 e0[16], e1[16];
  {
    const float wl0 = Wlin[0], bl0 = blin[0];
    #pragma unroll
    for (int i=0;i<16;i++){
      float a[4], c4[4];
      #pragma unroll
      for (int k2=0;k2<4;k2++){
        const int c = half*64 + i*4 + k2;
        if (c == 0){ a[k2] = fmaf(t0, wl0, bl0); c4[k2] = fmaf(t1, wl0, bl0); }
        else {
          const float wp = Wper[c-1], bp = bper[c-1];
          a[k2]  = __sinf(fmaf(t0, wp, bp));
          c4[k2] = __sinf(fmaf(t1, wp, bp));
        }
      }
      e0[i] = make_float4(a[0],a[1],a[2],a[3]);
      e1[i] = make_float4(c4[0],c4[1],c4[2],c4[3]);
    }
  }
  __syncthreads();

  for (int o=0;o<128;o++){
    const float4* wr = (const float4*)(Wl + o*ET + half*64);  // broadcast (2 addrs)
    float4 a0={0,0,0,0}, a1={0,0,0,0}, b0={0,0,0,0}, b1={0,0,0,0};
    #pragma unroll
    for (int i=0;i<8;i++){
      const float4 w0 = wr[2*i], w1 = wr[2*i+1];
      fma4(a0, w0, e0[2*i]); fma4(a1, w1, e0[2*i+1]);
      fma4(b0, w0, e1[2*i]); fma4(b1, w1, e1[2*i+1]);
    }
    float s0 = hsum4(a0) + hsum4(a1);
    float s1 = hsum4(b0) + hsum4(b1);
    s0 += __shfl_xor(s0, 1);
    s1 += __shfl_xor(s1, 1);
    if (half == 0){
      const float bb = bias[o];
      if (isq){
        Qbuf[((o>>4)*LQ + r     )*ETK + (o&15)] = __float2bfloat16((s0+bb)*0.25f);
        Qbuf[((o>>4)*LQ + r + 64)*ETK + (o&15)] = __float2bfloat16((s1+bb)*0.25f);
      } else {
        const int row_a = row0 + r, row_b = row0 + r + 64;
        const int ba = row_a >> 11, la = row_a & (LK-1);
        const int bb2 = row_b >> 11, lb = row_b & (LK-1);
        Kbuf[(((ba <<3)+(o>>4))*LK + la)*ETK + (o&15)] = __float2bfloat16(s0+bb);
        Kbuf[(((bb2<<3)+(o>>4))*LK + lb)*ETK + (o&15)] = __float2bfloat16(s1+bb);
      }
    }
  }
}

// ---------------------------------------------------------------------------
// Kernel 2: MFMA flash attention.  grid = B*H = 256 WGs, 256 thr = 4 waves.
// (unchanged — verified: absmax 2.4e-4)
// ---------------------------------------------------------------------------
__global__ __launch_bounds__(256, 2) void attn_mfma_kernel(
    const __hip_bfloat16* __restrict__ Kb, const __hip_bfloat16* __restrict__ Qb,
    const __hip_bfloat16* __restrict__ xT, float* __restrict__ attb)
{
  __shared__ uint4 Ks[2][512];    // 256 keys x 16 bf16 (2 units/row)
  __shared__ uint4 Xs[2][1024];   // 32 d x 256 keys (32 units/row)
  const int wgid = blockIdx.x;
  const int b = wgid >> 3, h = wgid & 7;
  const int tid = threadIdx.x;
  const int lane = tid & 63;
  const int ln = lane & 31, hi = lane >> 5;
  const int q0 = (tid >> 6) * 32;

  bf16x8 qf;
  {
    const uint4 u = *(const uint4*)(Qb + ((h*LQ + q0 + ln)*ETK + 8*hi));
    qf = *(const bf16x8*)&u;
  }

  const f32x16 zf = {0.f,0.f,0.f,0.f,0.f,0.f,0.f,0.f,0.f,0.f,0.f,0.f,0.f,0.f,0.f,0.f};
  f32x16 acc = zf;
  float m = -INFINITY, lsum = 0.f;

  const int sd = tid>>3, skb = (tid&7)*4, sdx = sd&7, ksw = (tid>>2)&7;
  const uint4* Kg = (const uint4*)(Kb + ((size_t)(b*Hn + h)*LK)*ETK);
  const uint4* Xg = (const uint4*)(xT + ((size_t)(b*Dn + sd))*LK + (tid&7)*32);

  uint4 kr0, kr1, xr0, xr1, xr2, xr3;
  {
    const uint4* kp = Kg + tid*2;
    kr0 = kp[0]; kr1 = kp[1];
    xr0 = Xg[0]; xr1 = Xg[1]; xr2 = Xg[2]; xr3 = Xg[3];
    Ks[0][(2*tid  ) ^ ksw] = kr0;
    Ks[0][(2*tid+1) ^ ksw] = kr1;
    Xs[0][sd*32 + ((skb+0)^sdx)] = xr0;
    Xs[0][sd*32 + ((skb+1)^sdx)] = xr1;
    Xs[0][sd*32 + ((skb+2)^sdx)] = xr2;
    Xs[0][sd*32 + ((skb+3)^sdx)] = xr3;
  }
  __syncthreads();

  for (int ck = 0; ck < 8; ck++){
    const int cur = ck & 1, nxt = cur ^ 1;
    if (ck < 7){
      const uint4* kp = Kg + ((ck+1)*256 + tid)*2;
      kr0 = kp[0]; kr1 = kp[1];
      const uint4* xp = Xg + (ck+1)*32;   // 256 keys = 512 B = 32 uint4 along row
      xr0 = xp[0]; xr1 = xp[1]; xr2 = xp[2]; xr3 = xp[3];
    }

    for (int kt = 0; kt < 8; kt++){
      const int r = kt*32 + ln;
      const uint4 ku = Ks[cur][(2*r + hi) ^ ((r>>2)&7)];
      const bf16x8 kf = *(const bf16x8*)&ku;
      f32x16 s = __builtin_amdgcn_mfma_f32_32x32x16_bf16(kf, qf, zf, 0, 0, 0);

      float tmax = s[0];
      #pragma unroll
      for (int i=1;i<16;i++) tmax = fmaxf(tmax, s[i]);
      tmax = fmaxf(tmax, __shfl_xor(tmax, 32));
      if (__any(tmax > m)){
        const float mn = fmaxf(m, tmax);
        const float al = __expf(m - mn);
        lsum *= al;
        acc *= al;
        m = mn;
      }
      float p[16]; float tsum = 0.f;
      #pragma unroll
      for (int i=0;i<16;i++){ p[i] = __expf(s[i] - m); tsum += p[i]; }
      tsum += __shfl_xor(tsum, 32);
      lsum += tsum;

      unsigned w0=pkbf(p[0],p[1]),  w1=pkbf(p[2],p[3]),  w2=pkbf(p[4],p[5]),  w3=pkbf(p[6],p[7]);
      unsigned w4=pkbf(p[8],p[9]),  w5=pkbf(p[10],p[11]),w6=pkbf(p[12],p[13]),w7=pkbf(p[14],p[15]);
      unsigned pw0=__shfl_xor(w0,32), pw1=__shfl_xor(w1,32), pw2=__shfl_xor(w2,32), pw3=__shfl_xor(w3,32);
      unsigned pw4=__shfl_xor(w4,32), pw5=__shfl_xor(w5,32), pw6=__shfl_xor(w6,32), pw7=__shfl_xor(w7,32);
      uint4 fa, fb;
      fa.x = hi ? pw2 : w0;  fa.y = hi ? pw3 : w1;
      fa.z = hi ? w2  : pw0; fa.w = hi ? w3  : pw1;
      fb.x = hi ? pw6 : w4;  fb.y = hi ? pw7 : w5;
      fb.z = hi ? w6  : pw4; fb.w = hi ? w7  : pw5;

      const int du = ln*32, dx = ln&7;
      const uint4 xa = Xs[cur][du + ((kt*4 + hi    )^dx)];
      const uint4 xb = Xs[cur][du + ((kt*4 + 2 + hi)^dx)];
      acc = __builtin_amdgcn_mfma_f32_32x32x16_bf16(*(const bf16x8*)&xa, *(const bf16x8*)&fa, acc, 0, 0, 0);
      acc = __builtin_amdgcn_mfma_f32_32x32x16_bf16(*(const bf16x8*)&xb, *(const bf16x8*)&fb, acc, 0, 0, 0);
    }

    if (ck < 7){
      Ks[nxt][(2*tid  ) ^ ksw] = kr0;
      Ks[nxt][(2*tid+1) ^ ksw] = kr1;
      Xs[nxt][sd*32 + ((skb+0)^sdx)] = xr0;
      Xs[nxt][sd*32 + ((skb+1)^sdx)] = xr1;
      Xs[nxt][sd*32 + ((skb+2)^sdx)] = xr2;
      Xs[nxt][sd*32 + ((skb+3)^sdx)] = xr3;
    }
    __syncthreads();
  }

  const float inv = 1.f / lsum;
  float* dst = attb + ((size_t)(b*LQ + q0 + ln)*(Hn*Dn) + h*Dn + 4*hi);
  #pragma unroll
  for (int g=0; g<4; g++){
    float4 v;
    v.x = acc[4*g+0]*inv; v.y = acc[4*g+1]*inv;
    v.z = acc[4*g+2]*inv; v.w = acc[4*g+3]*inv;
    *(float4*)(dst + g*8) = v;
  }
}

// ---------------------------------------------------------------------------
// Kernel 4: out = att @ Wo^T + bo. 16 rows/WG, weight half-rows in VGPRs.
// ---------------------------------------------------------------------------
__global__ __launch_bounds__(256, 1) void outproj_kernel(
    const float* __restrict__ att, const float* __restrict__ Wo, const float* __restrict__ bo,
    float* __restrict__ outb)
{
  __shared__ __align__(16) float a[16*256];   // 16 KB
  const int tid = threadIdx.x;
  const int o = tid>>1, half = tid&1;
  float4 w[32];
  {
    const float4* Wr = (const float4*)(Wo + o*256 + half*128);
    #pragma unroll
    for (int i=0;i<32;i++) w[i]=Wr[i];
  }
  const int row0 = blockIdx.x*16;
  {
    const float4* src = (const float4*)(att + (size_t)row0*256);
    float4* a4 = (float4*)a;
    #pragma unroll
    for (int i=0;i<4;i++) a4[tid + i*256] = src[tid + i*256];
  }
  __syncthreads();
  for (int r=0;r<16;r++){
    const float4* ar = (const float4*)(a + r*256 + half*128);
    float4 s4 = {0,0,0,0};
    #pragma unroll
    for (int i=0;i<32;i++) fma4(s4, w[i], ar[i]);
    float s = hsum4(s4);
    s += __shfl_xor(s, 1);
    if (half==0) outb[(size_t)(row0+r)*NH + o] = s + bo[o];
  }
}

// ---------------------------------------------------------------------------
// Kernel 5: x_gates = out @ W_ih^T + b_ih. 384 threads, full rows in VGPRs.
// ---------------------------------------------------------------------------
__global__ __launch_bounds__(384, 1) void gates_kernel(
    const float* __restrict__ outb, const float* __restrict__ W_ih, const float* __restrict__ b_ih,
    float* __restrict__ gates)
{
  __shared__ __align__(16) float a[16*128];   // 8 KB
  const int tid = threadIdx.x;
  float4 w[32];
  {
    const float4* Wr = (const float4*)(W_ih + (size_t)tid*NH);
    #pragma unroll
    for (int i=0;i<32;i++) w[i]=Wr[i];
  }
  const float bi = b_ih[tid];
  const int row0 = blockIdx.x*16;
  {
    const float4* src = (const float4*)(outb + (size_t)row0*NH);
    float4* a4 = (float4*)a;
    for (int i=tid; i<512; i+=384) a4[i] = src[i];
  }
  __syncthreads();
  for (int r=0;r<16;r++){
    const float4* ar = (const float4*)(a + r*NH);
    float4 s0={0,0,0,0}, s1={0,0,0,0};
    #pragma unroll
    for (int i=0;i<16;i++){ fma4(s0, w[2*i], ar[2*i]); fma4(s1, w[2*i+1], ar[2*i+1]); }
    gates[(size_t)(row0+r)*384 + tid] = hsum4(s0) + hsum4(s1) + bi;
  }
}

// ---------------------------------------------------------------------------
// Kernel 6: GRU scan (128 steps) + classifier MLP, one WG per batch element.
// Matvec via v_readlane: ONE ds_read_b128/thread/step (lane l&31 holds
// h[4l..4l+3]); h[k] pulled to SGPR with compile-time lane index and fed to
// v_fmac (SGPR operand). Kills the 192 redundant broadcast LDS reads/step
// that round-9 counters showed were the bottleneck (3100 cyc/step, 0 conflicts).
// ---------------------------------------------------------------------------
__global__ __launch_bounds__(384, 1) void gru_cls_kernel(
    const float* __restrict__ gates, const float* __restrict__ W_hh, const float* __restrict__ b_hh,
    const float* __restrict__ W1, const float* __restrict__ b1,
    const float* __restrict__ W2, const float* __restrict__ b2,
    const float* __restrict__ W3, const float* __restrict__ b3,
    float* __restrict__ out)
{
  __shared__ __align__(16) float h[128];
  __shared__ __align__(16) float hg[384];
  __shared__ __align__(16) float c1[304];
  __shared__ __align__(16) float c2[304];
  const int b = blockIdx.x, j = threadIdx.x;
  const int lane = j & 63;

  float4 w[32];
  {
    const float4* Wr = (const float4*)(W_hh + (size_t)j*NH);
    #pragma unroll
    for (int i=0;i<32;i++) w[i]=Wr[i];
  }
  const float bh = b_hh[j];

  float gxr=0.f, gxz=0.f, gxn=0.f;
  if (j < 128){
    const size_t gb = (size_t)b*LQ*384 + j;
    gxr = gates[gb]; gxz = gates[gb+128]; gxn = gates[gb+256];
    h[j] = 0.f;
  }
  __syncthreads();

  for (int tt=0; tt<LQ; tt++){
    float nxr=0.f, nxz=0.f, nxn=0.f;
    if (j < 128 && tt+1 < LQ){
      const size_t nb = ((size_t)b*LQ + tt + 1)*384 + j;
      nxr = gates[nb]; nxz = gates[nb+128]; nxn = gates[nb+256];
    }
    // one LDS read per thread: lane (l&31) holds h[4(l&31) .. +3]
    const float4 hv = ((const float4*)h)[lane & 31];
    float a0=0.f, a1=0.f, a2=0.f, a3=0.f;
    #pragma unroll
    for (int k=0;k<32;k++){
      a0 = fmaf(rdlane(hv.x, k), w[k].x, a0);
      a1 = fmaf(rdlane(hv.y, k), w[k].y, a1);
      a2 = fmaf(rdlane(hv.z, k), w[k].z, a2);
      a3 = fmaf(rdlane(hv.w, k), w[k].w, a3);
    }
    hg[j] = (a0+a1) + (a2+a3) + bh;
    __syncthreads();
    if (j < 128){
      const float r = 1.f/(1.f + __expf(-(gxr + hg[j])));
      const float z = 1.f/(1.f + __expf(-(gxz + hg[j+128])));
      const float n = 1.f - 2.f/(1.f + __expf(2.f*fmaf(r, hg[j+256], gxn)));
      h[j] = (1.f - z)*n + z*h[j];
      gxr = nxr; gxz = nxz; gxn = nxn;
    }
    __syncthreads();
  }

  if (j < 300){
    const float4* Wr1 = (const float4*)(W1 + (size_t)j*128);
    const float4* h4 = (const float4*)h;
    float4 s={0,0,0,0};
    #pragma unroll
    for (int i=0;i<32;i++) fma4(s, Wr1[i], h4[i]);
    c1[j] = fmaxf(hsum4(s) + b1[j], 0.f);
  }
  __syncthreads();
  if (j < 300){
    const float4* Wr2 = (const float4*)(W2 + (size_t)j*300);
    const float4* c14 = (const float4*)c1;
    float4 s={0,0,0,0};
    #pragma unroll
    for (int i=0;i<75;i++) fma4(s, Wr2[i], c14[i]);
    c2[j] = fmaxf(hsum4(s) + b2[j], 0.f);
  }
  __syncthreads();
  if (j < 2){
    const float4* Wr3 = (const float4*)(W3 + (size_t)j*300);
    const float4* c24 = (const float4*)c2;
    float4 s={0,0,0,0};
    #pragma unroll
    for (int i=0;i<75;i++) fma4(s, Wr3[i], c24[i]);
    out[b*2 + j] = hsum4(s) + b3[j];
  }
}

// ---------------------------------------------------------------------------
extern "C" void kernel_launch(void* const* d_in, const int* in_sizes, int n_in,
                              void* d_out, int out_size, void* d_ws, size_t ws_size,
                              hipStream_t stream)
{
  const float* x    = (const float*)d_in[0];
  const float* ts   = (const float*)d_in[1];
  const float* qt   = (const float*)d_in[2];
  const float* Wlin = (const float*)d_in[3];
  const float* blin = (const float*)d_in[4];
  const float* Wper = (const float*)d_in[5];
  const float* bper = (const float*)d_in[6];
  const float* Wq   = (const float*)d_in[7];
  const float* bq   = (const float*)d_in[8];
  const float* Wk   = (const float*)d_in[9];
  const float* bk   = (const float*)d_in[10];
  const float* Wo   = (const float*)d_in[11];
  const float* bo   = (const float*)d_in[12];
  const float* W_ih = (const float*)d_in[13];
  const float* b_ih = (const float*)d_in[14];
  const float* W_hh = (const float*)d_in[15];
  const float* b_hh = (const float*)d_in[16];
  const float* W1   = (const float*)d_in[17];
  const float* b1   = (const float*)d_in[18];
  const float* W2   = (const float*)d_in[19];
  const float* b2   = (const float*)d_in[20];
  const float* W3   = (const float*)d_in[21];
  const float* b3   = (const float*)d_in[22];
  float* out = (float*)d_out;

  // workspace layout
  __hip_bfloat16* Kbb = (__hip_bfloat16*)d_ws;            // B*H*LK*16 = 8,388,608 bf16
  __hip_bfloat16* Qbb = Kbb + 8388608;                    // H*LQ*16   = 16,384 bf16
  __hip_bfloat16* xTb = Qbb + 16384;                      // B*32*LK   = 2,097,152 bf16
  float* attb = (float*)(xTb + 2097152);                  // B*LQ*256  = 1,048,576 f32
  float* outb = attb + 1048576;                           // B*LQ*128  = 524,288 f32
  float* gts  = outb + 524288;                            // B*LQ*384  = 1,572,864 f32
  (void)ws_size; (void)in_sizes; (void)n_in; (void)out_size;

  xt_kernel      <<<dim3(1024), dim3(256), 0, stream>>>(x, xTb);
  proj_kernel    <<<dim3(513),  dim3(128), 0, stream>>>(ts, qt, Wlin, blin, Wper, bper, Wq, bq, Wk, bk, Kbb, Qbb);
  attn_mfma_kernel<<<dim3(256), dim3(256), 0, stream>>>(Kbb, Qbb, xTb, attb);
  outproj_kernel <<<dim3(256),  dim3(256), 0, stream>>>(attb, Wo, bo, outb);
  gates_kernel   <<<dim3(256),  dim3(384), 0, stream>>>(outb, W_ih, b_ih, gts);
  gru_cls_kernel <<<dim3(32),   dim3(384), 0, stream>>>(gts, W_hh, b_hh, W1, b1, W2, b2, W3, b3, out);
}